// Round 5
// baseline (2334.611 us; speedup 1.0000x reference)
//
#include <hip/hip_runtime.h>
#include <hip/hip_bf16.h>

// ---------------- problem dims ----------------
#define BB 512   // batch
#define TT 96    // encoder length
#define FF 32    // features
#define HH 512   // hidden
#define PP 48    // pred length

// ---------------- kernel config ----------------
// 256 WGs x 256 threads, 1 WG/CU (LDS-forced), all co-resident.
// group = blockIdx & 15  -> batch rows [grp*32, grp*32+32)
// cslice = blockIdx >> 4 -> hidden units [cslice*32, cslice*32+32) x 4 gates = 128 gate cols
#define NGRP   16
#define ROWS   32
#define NHID   32
#define GCOL   128
#define KCH    16    // K chunks of 32 over H=512
#define SCH    64    // 8-elem subchunks for H part
#define SCW    68    // + 4 subchunks for x part (F=32)
#define WPAD   129   // padded col count in weight tile (16B units)
#define GPAD   132   // padded gate-row stride (floats)

typedef __bf16 v8bf __attribute__((ext_vector_type(8)));
typedef float  v4f  __attribute__((ext_vector_type(4)));
typedef unsigned long long u64;

__device__ __forceinline__ float sigf(float x) { return 1.f / (1.f + __expf(-x)); }
__device__ __forceinline__ float tanh_(float x) {
  float t = __expf(-2.f * fabsf(x));
  float r = (1.f - t) / (1.f + t);
  return copysignf(r, x);
}
__device__ __forceinline__ unsigned short f2bf_raw(float x) {
  __hip_bfloat16 h = __float2bfloat16(x);
  unsigned short r; __builtin_memcpy(&r, &h, 2); return r;
}

// ---------------- dtype detector ----------------
// Interpret first 1024 u16 of enc_Whh (~U(-0.044,0.044)) as bf16. True bf16:
// every exponent field < 0x80. fp32: mantissa halves uniform -> flag=0.
__global__ void detect_dtype(const unsigned short* __restrict__ w, unsigned* __restrict__ flag) {
  bool bad = false;
  for (int i = threadIdx.x; i < 1024; i += 64) {
    unsigned e = (w[i] >> 7) & 0xFF;
    if (e >= 0x80) bad = true;
  }
  bool any = __any(bad);
  if (threadIdx.x == 0) *flag = any ? 0u : 1u;  // 1 = bf16, 0 = fp32
}

// ---------------- canonicalize: src (bf16 or fp32 per flag) -> bf16 ----------------
__global__ void canon(const void* __restrict__ src, __hip_bfloat16* __restrict__ dst,
                      int n, const unsigned* __restrict__ flag) {
  const int i = (blockIdx.x * 256 + threadIdx.x) * 8;
  if (i >= n) return;
  if (*flag) {
    *(uint4*)&dst[i] = *(const uint4*)((const __hip_bfloat16*)src + i);
  } else {
    const float* s = (const float*)src + i;
    uint4 lo = *(const uint4*)s, hi = *(const uint4*)(s + 4);
    union { unsigned short r[8]; uint4 q; } o;
    const float* f0 = (const float*)&lo;
    const float* f1 = (const float*)&hi;
#pragma unroll
    for (int j = 0; j < 4; ++j) { o.r[j] = f2bf_raw(f0[j]); o.r[4 + j] = f2bf_raw(f1[j]); }
    *(uint4*)&dst[i] = o.q;
  }
}

// Weight tile loader: LDS layout [sc][col][8 bf16], col = gate*32 + j.
template<int NSC>
__device__ void load_wtile(const __hip_bfloat16* __restrict__ whh,
                           const __hip_bfloat16* __restrict__ wih,
                           const __hip_bfloat16* __restrict__ bias_bf,
                           const float* __restrict__ bias_f,
                           int cslice, __hip_bfloat16* wt, float* bs) {
  const int total = NSC * GCOL;
  for (int u = threadIdx.x; u < total; u += 256) {
    const int l = u / NSC, sc = u % NSC;
    const int gcol = (l >> 5) * HH + cslice * NHID + (l & 31);
    const __hip_bfloat16* src = (sc < SCH) ? (whh + (size_t)gcol * HH + sc * 8)
                                           : (wih + (size_t)gcol * FF + (sc - SCH) * 8);
    *(uint4*)&wt[((size_t)sc * WPAD + l) * 8] = *(const uint4*)src;
  }
  if (threadIdx.x < GCOL) {
    const int l = threadIdx.x;
    const int gcol = (l >> 5) * HH + cslice * NHID + (l & 31);
    bs[l] = bias_f ? bias_f[gcol] : __bfloat162float(bias_bf[gcol]);
  }
}

// One fused LSTM step: gates GEMM (MFMA) + gate nonlinearity + h write + group barrier.
// NSC=68: K = 512(h) + 32(x).  NSC=64: K = 512 (folded decoder).
// RIDER: col-WGs 0/1, waves 0/1 additionally compute out_{d-1} = h_{d-1}@linW^T + lin_b
// from the same A-fragments. OUTPUT IS FP32.
template<int NSC, bool RIDER>
__device__ __forceinline__ void lstm_step(
    int grp, int cslice, int tid,
    const __hip_bfloat16* __restrict__ hsrc,
    __hip_bfloat16* __restrict__ hdst,
    const __hip_bfloat16* __restrict__ xbase,   // c_inp + t*FF (row stride TT*FF)
    const __hip_bfloat16* __restrict__ linW, float linb,
    float* __restrict__ outp,                   // d_out + (d-1)*FF, fp32
    const __hip_bfloat16* __restrict__ wt,
    const float* __restrict__ bs,
    float* __restrict__ gl,
    float c[4],
    unsigned* cnt, unsigned target)
{
  const int w = tid >> 6, lane = tid & 63;
  const int arow = grp * ROWS + (w & 1) * 16 + (lane & 15);
  const int koff = (lane >> 4) * 8;
  const int ntbase = (w >> 1) * 4;

  // ---- A prefetch: coherent (agent-scope) loads of h ----
  u64 a0[KCH], a1[KCH];
  {
    const char* hb = (const char*)hsrc + ((size_t)arow * HH + koff) * 2;
#pragma unroll
    for (int kc = 0; kc < KCH; ++kc) {
      a0[kc] = __hip_atomic_load((const u64*)(hb + kc * 64),     __ATOMIC_RELAXED, __HIP_MEMORY_SCOPE_AGENT);
      a1[kc] = __hip_atomic_load((const u64*)(hb + kc * 64 + 8), __ATOMIC_RELAXED, __HIP_MEMORY_SCOPE_AGENT);
    }
  }
  uint4 xv = make_uint4(0u, 0u, 0u, 0u);
  if constexpr (NSC == SCW) {
    xv = *(const uint4*)((const char*)xbase + ((size_t)arow * TT * FF + koff) * 2);
  }

  v4f acc[4] = {{0,0,0,0},{0,0,0,0},{0,0,0,0},{0,0,0,0}};
  v4f oacc = {0,0,0,0};

#pragma unroll
  for (int kc = 0; kc < NSC / 4; ++kc) {
    v8bf av;
    if (kc < KCH) { union { u64 q[2]; v8bf v; } u_; u_.q[0] = a0[kc]; u_.q[1] = a1[kc]; av = u_.v; }
    else          { union { uint4 q; v8bf v; } u_; u_.q = xv; av = u_.v; }
    const int sc = kc * 4 + (lane >> 4);
#pragma unroll
    for (int n = 0; n < 4; ++n) {
      v8bf bv = *(const v8bf*)&wt[((size_t)sc * WPAD + (ntbase + n) * 16 + (lane & 15)) * 8];
      acc[n] = __builtin_amdgcn_mfma_f32_16x16x32_bf16(av, bv, acc[n], 0, 0, 0);
    }
    if constexpr (RIDER) {
      if (kc < KCH && cslice < 2 && w < 2) {
        v8bf bl = *(const v8bf*)((const char*)linW +
                   ((size_t)(cslice * 16 + (lane & 15)) * HH + kc * 32 + koff) * 2);
        oacc = __builtin_amdgcn_mfma_f32_16x16x32_bf16(av, bl, oacc, 0, 0, 0);
      }
    }
  }

  // ---- stage gates to LDS (fp32) ----
  {
    const int gr = (w & 1) * 16 + (lane >> 4) * 4;
#pragma unroll
    for (int n = 0; n < 4; ++n)
#pragma unroll
      for (int r = 0; r < 4; ++r)
        gl[(gr + r) * GPAD + (ntbase + n) * 16 + (lane & 15)] = acc[n][r];
  }

  if constexpr (RIDER) {
    if (cslice < 2 && w < 2) {
#pragma unroll
      for (int r = 0; r < 4; ++r) {
        int brow = grp * ROWS + (w & 1) * 16 + (lane >> 4) * 4 + r;
        outp[(size_t)brow * PP * FF + cslice * 16 + (lane & 15)] = oacc[r] + linb;  // fp32 store
      }
    }
  }

  __syncthreads();

  // ---- gate nonlinearities + state update (thread -> row tid>>3, units (tid&7)*4..+3) ----
  {
    const int er = tid >> 3;
    const int ej = (tid & 7) * 4;
    v4f gi = *(const v4f*)&gl[er * GPAD + 0 * NHID + ej];
    v4f gf = *(const v4f*)&gl[er * GPAD + 1 * NHID + ej];
    v4f gg = *(const v4f*)&gl[er * GPAD + 2 * NHID + ej];
    v4f go = *(const v4f*)&gl[er * GPAD + 3 * NHID + ej];
    v4f bi = *(const v4f*)&bs[0 * NHID + ej];
    v4f bf_ = *(const v4f*)&bs[1 * NHID + ej];
    v4f bg = *(const v4f*)&bs[2 * NHID + ej];
    v4f bo = *(const v4f*)&bs[3 * NHID + ej];
    union { unsigned short s[4]; u64 q; } hq;
#pragma unroll
    for (int u2 = 0; u2 < 4; ++u2) {
      float iv = sigf(gi[u2] + bi[u2]);
      float fv = sigf(gf[u2] + bf_[u2]);
      float gv = tanh_(gg[u2] + bg[u2]);
      float ov = sigf(go[u2] + bo[u2]);
      c[u2] = fv * c[u2] + iv * gv;
      float hv = ov * tanh_(c[u2]);
      hq.s[u2] = f2bf_raw(hv);
    }
    __hip_atomic_store((u64*)((char*)hdst + ((size_t)(grp * ROWS + er) * HH + cslice * NHID + ej) * 2),
                       hq.q, __ATOMIC_RELAXED, __HIP_MEMORY_SCOPE_AGENT);
  }

  // ---- group barrier: 16 WGs, monotonic counter; only tid 0 releases + polls ----
  __syncthreads();  // all this WG's h-stores drained (vmcnt) before release
  if (tid == 0) {
    __hip_atomic_fetch_add(cnt, 1u, __ATOMIC_RELEASE, __HIP_MEMORY_SCOPE_AGENT);
    while (__hip_atomic_load(cnt, __ATOMIC_RELAXED, __HIP_MEMORY_SCOPE_AGENT) < target)
      __builtin_amdgcn_s_sleep(1);
  }
  __syncthreads();
  __builtin_amdgcn_fence(__ATOMIC_ACQUIRE, "agent");
}

__global__ void __launch_bounds__(256, 1) seq_main(
    const __hip_bfloat16* __restrict__ inp,
    const __hip_bfloat16* __restrict__ eWih, const __hip_bfloat16* __restrict__ eWhh,
    const __hip_bfloat16* __restrict__ eB,
    const __hip_bfloat16* __restrict__ dWih, const __hip_bfloat16* __restrict__ dWhh,
    const __hip_bfloat16* __restrict__ dB,
    const __hip_bfloat16* __restrict__ linW, const __hip_bfloat16* __restrict__ linB,
    const __hip_bfloat16* __restrict__ wEff, const float* __restrict__ bEff,
    __hip_bfloat16* __restrict__ hbuf, unsigned* __restrict__ cnt,
    float* __restrict__ out)
{
  __shared__ __align__(16) __hip_bfloat16 wt[SCW * WPAD * 8];  // 140352 B
  __shared__ float gl[ROWS * GPAD];                            // 16896 B
  __shared__ float bs[GCOL];                                   // 512 B
  const int tid = threadIdx.x;
  const int grp = blockIdx.x & 15;
  const int cslice = blockIdx.x >> 4;
  unsigned* mycnt = cnt + grp * 32;
  float c[4] = {0.f, 0.f, 0.f, 0.f};
  unsigned gen = 0;
  int cur = 0;

  // -------- encoder --------
  load_wtile<SCW>(eWhh, eWih, eB, nullptr, cslice, wt, bs);
  __syncthreads();
  for (int t = 0; t < TT; ++t) {
    lstm_step<SCW, false>(grp, cslice, tid,
        hbuf + (size_t)cur * BB * HH, hbuf + (size_t)(cur ^ 1) * BB * HH,
        inp + (size_t)t * FF, nullptr, 0.f, nullptr, wt, bs, gl, c, mycnt, 16u * (++gen));
    cur ^= 1;
  }

  // -------- decoder step 0: x = input[:, T-1, :], weights = dec --------
  __syncthreads();
  load_wtile<SCW>(dWhh, dWih, dB, nullptr, cslice, wt, bs);
  __syncthreads();
  lstm_step<SCW, false>(grp, cslice, tid,
      hbuf + (size_t)cur * BB * HH, hbuf + (size_t)(cur ^ 1) * BB * HH,
      inp + (size_t)(TT - 1) * FF, nullptr, 0.f, nullptr, wt, bs, gl, c, mycnt, 16u * (++gen));
  cur ^= 1;

  // -------- decoder steps 1..47 (folded), out_{d-1} rides along --------
  __syncthreads();
  load_wtile<SCH>(wEff, nullptr, nullptr, bEff, cslice, wt, bs);
  __syncthreads();
  const float linb = (cslice < 2) ? __bfloat162float(linB[cslice * 16 + (tid & 15)]) : 0.f;
  for (int d = 1; d < PP; ++d) {
    lstm_step<SCH, true>(grp, cslice, tid,
        hbuf + (size_t)cur * BB * HH, hbuf + (size_t)(cur ^ 1) * BB * HH,
        nullptr, linW, linb, out + (size_t)(d - 1) * FF, wt, bs, gl, c, mycnt, 16u * (++gen));
    cur ^= 1;
  }

  // -------- tail: out_47 from final h --------
  if (cslice < 2) {
    const int w = tid >> 6, lane = tid & 63;
    if (w < 2) {
      const int arow = grp * ROWS + w * 16 + (lane & 15);
      const int koff = (lane >> 4) * 8;
      const char* hb = (const char*)(hbuf + (size_t)cur * BB * HH) + ((size_t)arow * HH + koff) * 2;
      v4f oacc = {0, 0, 0, 0};
#pragma unroll
      for (int kc = 0; kc < KCH; ++kc) {
        union { u64 q[2]; v8bf v; } u_;
        u_.q[0] = __hip_atomic_load((const u64*)(hb + kc * 64),     __ATOMIC_RELAXED, __HIP_MEMORY_SCOPE_AGENT);
        u_.q[1] = __hip_atomic_load((const u64*)(hb + kc * 64 + 8), __ATOMIC_RELAXED, __HIP_MEMORY_SCOPE_AGENT);
        v8bf bl = *(const v8bf*)((const char*)linW +
                   ((size_t)(cslice * 16 + (lane & 15)) * HH + kc * 32 + koff) * 2);
        oacc = __builtin_amdgcn_mfma_f32_16x16x32_bf16(u_.v, bl, oacc, 0, 0, 0);
      }
      const float lb = __bfloat162float(linB[cslice * 16 + (lane & 15)]);
#pragma unroll
      for (int r = 0; r < 4; ++r) {
        int brow = grp * ROWS + w * 16 + (lane >> 4) * 4 + r;
        out[(size_t)brow * PP * FF + (size_t)(PP - 1) * FF + cslice * 16 + (lane & 15)] =
            oacc[r] + lb;  // fp32 store
      }
    }
  }
}

// ---- setup: zero h0 + barrier counters, b_eff = dec_b + Wih_dec @ lin_b ----
__global__ void setup_misc(const __hip_bfloat16* __restrict__ dWih,
                           const __hip_bfloat16* __restrict__ dB,
                           const __hip_bfloat16* __restrict__ linB,
                           __hip_bfloat16* __restrict__ hbuf,
                           float* __restrict__ bEff, unsigned* __restrict__ cnt) {
  const int idx = blockIdx.x * 256 + threadIdx.x;
  if (idx < BB * HH / 2) ((unsigned*)hbuf)[idx] = 0u;
  if (idx < NGRP * 32) cnt[idx] = 0u;
  if (idx < 4 * HH) {
    float a = __bfloat162float(dB[idx]);
#pragma unroll 8
    for (int f = 0; f < FF; ++f)
      a += __bfloat162float(dWih[(size_t)idx * FF + f]) * __bfloat162float(linB[f]);
    bEff[idx] = a;
  }
}

// ---- setup: W_eff[n][k] = Whh_dec[n][k] + sum_f lin_W[f][k] * Wih_dec[n][f] ----
__global__ void setup_weff(const __hip_bfloat16* __restrict__ dWhh,
                           const __hip_bfloat16* __restrict__ dWih,
                           const __hip_bfloat16* __restrict__ linW,
                           __hip_bfloat16* __restrict__ wEff) {
  const int idx = blockIdx.x * 256 + threadIdx.x;
  const int n = idx >> 9, k = idx & 511;
  float a = __bfloat162float(dWhh[idx]);
#pragma unroll 8
  for (int f = 0; f < FF; ++f)
    a += __bfloat162float(linW[(size_t)f * HH + k]) * __bfloat162float(dWih[(size_t)n * FF + f]);
  wEff[idx] = __float2bfloat16(a);
}

extern "C" void kernel_launch(void* const* d_in, const int* in_sizes, int n_in,
                              void* d_out, int out_size, void* d_ws, size_t ws_size,
                              hipStream_t stream) {
  (void)in_sizes; (void)n_in; (void)out_size; (void)ws_size;
  char* ws = (char*)d_ws;
  // ---- workspace layout (bytes) ----
  unsigned*       flag = (unsigned*)ws;                              // @0
  unsigned*       cnt  = (unsigned*)(ws + 256);                      // 2048 B
  float*          bEff = (float*)(ws + 4096);                        // 8192 B
  __hip_bfloat16* hbuf = (__hip_bfloat16*)(ws + 12288);              // 1 MiB
  __hip_bfloat16* wEff = (__hip_bfloat16*)(ws + 12288 + 1048576);    // 2 MiB
  char* cbase = ws + 12288 + 1048576 + 2097152;
  __hip_bfloat16* c_inp  = (__hip_bfloat16*)(cbase);                 // 3,145,728 B
  __hip_bfloat16* c_eWih = (__hip_bfloat16*)(cbase + 3145728);
  __hip_bfloat16* c_eWhh = (__hip_bfloat16*)(cbase + 3276800);
  __hip_bfloat16* c_eB   = (__hip_bfloat16*)(cbase + 5373952);
  __hip_bfloat16* c_dWih = (__hip_bfloat16*)(cbase + 5378048);
  __hip_bfloat16* c_dWhh = (__hip_bfloat16*)(cbase + 5509120);
  __hip_bfloat16* c_dB   = (__hip_bfloat16*)(cbase + 7606272);
  __hip_bfloat16* c_linW = (__hip_bfloat16*)(cbase + 7610368);
  __hip_bfloat16* c_linB = (__hip_bfloat16*)(cbase + 7643136);

  detect_dtype<<<dim3(1), dim3(64), 0, stream>>>((const unsigned short*)d_in[4], flag);

  struct { int idx; __hip_bfloat16* dst; int n; } jobs[9] = {
    {0, c_inp,  BB * TT * FF}, {3, c_eWih, 4 * HH * FF}, {4, c_eWhh, 4 * HH * HH},
    {5, c_eB,   4 * HH},       {6, c_dWih, 4 * HH * FF}, {7, c_dWhh, 4 * HH * HH},
    {8, c_dB,   4 * HH},       {9, c_linW, FF * HH},     {10, c_linB, FF},
  };
  for (int j = 0; j < 9; ++j) {
    int blocks = (jobs[j].n / 8 + 255) / 256;
    canon<<<dim3(blocks), dim3(256), 0, stream>>>(d_in[jobs[j].idx], jobs[j].dst, jobs[j].n, flag);
  }

  setup_misc<<<dim3(512), dim3(256), 0, stream>>>(c_dWih, c_dB, c_linB, hbuf, bEff, cnt);
  setup_weff<<<dim3(4096), dim3(256), 0, stream>>>(c_dWhh, c_dWih, c_linW, wEff);
  seq_main<<<dim3(256), dim3(256), 0, stream>>>(c_inp, c_eWih, c_eWhh, c_eB,
                                                c_dWih, c_dWhh, c_dB,
                                                c_linW, c_linB, wEff, bEff, hbuf, cnt,
                                                (float*)d_out);
}

// Round 6
// 927.707 us; speedup vs baseline: 2.5165x; 2.5165x over previous
//
#include <hip/hip_runtime.h>
#include <hip/hip_bf16.h>

// ---------------- problem dims ----------------
#define BB 512   // batch
#define TT 96    // encoder length
#define FF 32    // features
#define HH 512   // hidden
#define PP 48    // pred length

// 256 WGs x 256 threads, 1 WG/CU (LDS-forced), all co-resident.
// grp = blockIdx & 15  -> batch rows [grp*32, +32)
// cslice = blockIdx >> 4 -> hidden units [cslice*32, +32) x 4 gates
// Transposed GEMM: gates^T = W * h^T. A = weights (LDS), B = h rows (global).
// Thread (w, lane): batch row brow = grp*32 + (w&1)*16 + (lane&15),
// owns units j0..j0+3 (j0 = (w>>1)*16 + (lane>>4)*4) with all 4 gates in acc[n][r].
#define NGRP   16
#define ROWS   32
#define NHID   32
#define GCOL   128
#define KCH    16    // K chunks of 32 over H=512
#define SCH    64    // 8-elem subchunks for H part
#define SCW    68    // + 4 subchunks for x part (F=32)
#define WPAD   129   // padded col count in weight tile (16B units)

typedef __bf16 v8bf __attribute__((ext_vector_type(8)));
typedef float  v4f  __attribute__((ext_vector_type(4)));
typedef unsigned int u32x4 __attribute__((ext_vector_type(4)));
typedef unsigned long long u64;

__device__ __forceinline__ float sigf(float x) { return 1.f / (1.f + __expf(-x)); }
__device__ __forceinline__ float tanh_(float x) {
  float t = __expf(-2.f * fabsf(x));
  float r = (1.f - t) / (1.f + t);
  return copysignf(r, x);
}
__device__ __forceinline__ unsigned short f2bf_raw(float x) {
  __hip_bfloat16 h = __float2bfloat16(x);
  unsigned short r; __builtin_memcpy(&r, &h, 2); return r;
}

// Coherent (LLC-direct) load of 16x16B strided h fragments; waitcnt inside the
// asm block so consumers can only see post-completion values.
__device__ __forceinline__ void coh_load_h(u32x4 hb[16], const void* hp) {
  asm volatile(
    "global_load_dwordx4 %0, %16, off sc0 sc1\n\t"
    "global_load_dwordx4 %1, %16, off offset:64 sc0 sc1\n\t"
    "global_load_dwordx4 %2, %16, off offset:128 sc0 sc1\n\t"
    "global_load_dwordx4 %3, %16, off offset:192 sc0 sc1\n\t"
    "global_load_dwordx4 %4, %16, off offset:256 sc0 sc1\n\t"
    "global_load_dwordx4 %5, %16, off offset:320 sc0 sc1\n\t"
    "global_load_dwordx4 %6, %16, off offset:384 sc0 sc1\n\t"
    "global_load_dwordx4 %7, %16, off offset:448 sc0 sc1\n\t"
    "global_load_dwordx4 %8, %16, off offset:512 sc0 sc1\n\t"
    "global_load_dwordx4 %9, %16, off offset:576 sc0 sc1\n\t"
    "global_load_dwordx4 %10, %16, off offset:640 sc0 sc1\n\t"
    "global_load_dwordx4 %11, %16, off offset:704 sc0 sc1\n\t"
    "global_load_dwordx4 %12, %16, off offset:768 sc0 sc1\n\t"
    "global_load_dwordx4 %13, %16, off offset:832 sc0 sc1\n\t"
    "global_load_dwordx4 %14, %16, off offset:896 sc0 sc1\n\t"
    "global_load_dwordx4 %15, %16, off offset:960 sc0 sc1\n\t"
    "s_waitcnt vmcnt(0)"
    : "=&v"(hb[0]), "=&v"(hb[1]), "=&v"(hb[2]), "=&v"(hb[3]),
      "=&v"(hb[4]), "=&v"(hb[5]), "=&v"(hb[6]), "=&v"(hb[7]),
      "=&v"(hb[8]), "=&v"(hb[9]), "=&v"(hb[10]), "=&v"(hb[11]),
      "=&v"(hb[12]), "=&v"(hb[13]), "=&v"(hb[14]), "=&v"(hb[15])
    : "v"(hp)
    : "memory");
}

// ---------------- dtype detector (inputs are fp32; keep robust) ----------------
__global__ void detect_dtype(const unsigned short* __restrict__ w, unsigned* __restrict__ flag) {
  bool bad = false;
  for (int i = threadIdx.x; i < 1024; i += 64) {
    unsigned e = (w[i] >> 7) & 0xFF;
    if (e >= 0x80) bad = true;
  }
  bool any = __any(bad);
  if (threadIdx.x == 0) *flag = any ? 0u : 1u;  // 1 = bf16, 0 = fp32
}

// ---------------- canonicalize: src (bf16 or fp32 per flag) -> bf16 ----------------
__global__ void canon(const void* __restrict__ src, __hip_bfloat16* __restrict__ dst,
                      int n, const unsigned* __restrict__ flag) {
  const int i = (blockIdx.x * 256 + threadIdx.x) * 8;
  if (i >= n) return;
  if (*flag) {
    *(uint4*)&dst[i] = *(const uint4*)((const __hip_bfloat16*)src + i);
  } else {
    const float* s = (const float*)src + i;
    uint4 lo = *(const uint4*)s, hi = *(const uint4*)(s + 4);
    union { unsigned short r[8]; uint4 q; } o;
    const float* f0 = (const float*)&lo;
    const float* f1 = (const float*)&hi;
#pragma unroll
    for (int j = 0; j < 4; ++j) { o.r[j] = f2bf_raw(f0[j]); o.r[4 + j] = f2bf_raw(f1[j]); }
    *(uint4*)&dst[i] = o.q;
  }
}

// Weight tile loader (unchanged layout): LDS [sc][col l][8 bf16], l = gate*32 + unit.
template<int NSC>
__device__ void load_wtile(const __hip_bfloat16* __restrict__ whh,
                           const __hip_bfloat16* __restrict__ wih,
                           const __hip_bfloat16* __restrict__ bias_bf,
                           const float* __restrict__ bias_f,
                           int cslice, __hip_bfloat16* wt, float* bs) {
  const int total = NSC * GCOL;
  for (int u = threadIdx.x; u < total; u += 256) {
    const int l = u / NSC, sc = u % NSC;
    const int gcol = (l >> 5) * HH + cslice * NHID + (l & 31);
    const __hip_bfloat16* src = (sc < SCH) ? (whh + (size_t)gcol * HH + sc * 8)
                                           : (wih + (size_t)gcol * FF + (sc - SCH) * 8);
    *(uint4*)&wt[((size_t)sc * WPAD + l) * 8] = *(const uint4*)src;
  }
  if (threadIdx.x < GCOL) {
    const int l = threadIdx.x;
    const int gcol = (l >> 5) * HH + cslice * NHID + (l & 31);
    bs[l] = bias_f ? bias_f[gcol] : __bfloat162float(bias_bf[gcol]);
  }
}

// One fused LSTM step, transposed GEMM, register-local gates, flag barrier.
template<int NSC, bool RIDER>
__device__ __forceinline__ void lstm_step(
    int tid, int cslice,
    const char* hp, char* hw, const char* xp,
    const __hip_bfloat16* __restrict__ linW, const float* lb4, float* op,
    const __hip_bfloat16* __restrict__ wt, const v4f* bb,
    float c4[4], const unsigned char* fl, unsigned char* myfl, unsigned gen)
{
  const int w = tid >> 6, lane = tid & 63;
  u32x4 hb[16];
  coh_load_h(hb, hp);
  u32x4 xv = {0u, 0u, 0u, 0u};
  if constexpr (NSC == SCW) xv = *(const u32x4*)xp;

  v4f acc[4] = {{0,0,0,0},{0,0,0,0},{0,0,0,0},{0,0,0,0}};
  v4f oacc = {0,0,0,0};
  const int abase = (w >> 1) * 16 + (lane & 15);

#pragma unroll
  for (int kc = 0; kc < NSC / 4; ++kc) {
    v8bf bv;
    if (kc < KCH) { union { u32x4 q; v8bf v; } u_; u_.q = hb[kc]; bv = u_.v; }
    else          { union { u32x4 q; v8bf v; } u_; u_.q = xv;     bv = u_.v; }
    const int sc = kc * 4 + (lane >> 4);
#pragma unroll
    for (int n = 0; n < 4; ++n) {
      v8bf av = *(const v8bf*)&wt[((size_t)sc * WPAD + n * 32 + abase) * 8];
      acc[n] = __builtin_amdgcn_mfma_f32_16x16x32_bf16(av, bv, acc[n], 0, 0, 0);
    }
    if constexpr (RIDER) {
      if (kc < KCH && cslice < 2 && w < 2) {
        v8bf al = *(const v8bf*)((const char*)linW +
                   ((size_t)(cslice * 16 + (lane & 15)) * HH + kc * 32 + (lane >> 4) * 8) * 2);
        oacc = __builtin_amdgcn_mfma_f32_16x16x32_bf16(al, bv, oacc, 0, 0, 0);
      }
    }
  }

  // ---- gate nonlinearities, fully in registers (acc[gate][r] for unit j0+r) ----
  union { unsigned short s[4]; u64 q; } hq;
#pragma unroll
  for (int r = 0; r < 4; ++r) {
    float iv = sigf(acc[0][r] + bb[0][r]);
    float fv = sigf(acc[1][r] + bb[1][r]);
    float gv = tanh_(acc[2][r] + bb[2][r]);
    float ov = sigf(acc[3][r] + bb[3][r]);
    c4[r] = fv * c4[r] + iv * gv;
    hq.s[r] = f2bf_raw(ov * tanh_(c4[r]));
  }
  asm volatile("global_store_dwordx2 %0, %1, off sc0 sc1" :: "v"(hw), "v"(hq.q) : "memory");

  if constexpr (RIDER) {
    if (cslice < 2 && w < 2) {
      v4f ovv;
#pragma unroll
      for (int r = 0; r < 4; ++r) ovv[r] = oacc[r] + lb4[r];
      *(v4f*)op = ovv;  // plain fp32 store to d_out
    }
  }

  // ---- flag barrier: drain stores, publish gen, poll 16 bytes ----
  asm volatile("s_waitcnt vmcnt(0)" ::: "memory");
  __syncthreads();
  if (tid == 0) {
    unsigned g = gen;
    asm volatile("global_store_byte %0, %1, off sc0 sc1" :: "v"(myfl), "v"(g) : "memory");
  }
  if (tid < 16) {
    const unsigned char* p = fl + tid;
    unsigned v;
    while (1) {
      asm volatile("global_load_ubyte %0, %1, off sc0 sc1\n\ts_waitcnt vmcnt(0)"
                   : "=v"(v) : "v"(p) : "memory");
      if (v >= gen) break;
      __builtin_amdgcn_s_sleep(1);
    }
  }
  __syncthreads();
}

__global__ void __launch_bounds__(256, 1) seq_main(
    const __hip_bfloat16* __restrict__ inp,
    const __hip_bfloat16* __restrict__ eWih, const __hip_bfloat16* __restrict__ eWhh,
    const __hip_bfloat16* __restrict__ eB,
    const __hip_bfloat16* __restrict__ dWih, const __hip_bfloat16* __restrict__ dWhh,
    const __hip_bfloat16* __restrict__ dB,
    const __hip_bfloat16* __restrict__ linW, const __hip_bfloat16* __restrict__ linB,
    const __hip_bfloat16* __restrict__ wEff, const float* __restrict__ bEff,
    __hip_bfloat16* __restrict__ hbuf, unsigned char* __restrict__ flags,
    float* __restrict__ out)
{
  __shared__ __align__(16) __hip_bfloat16 wt[SCW * WPAD * 8];  // 140352 B
  __shared__ float bs[GCOL];
  const int tid = threadIdx.x;
  const int grp = blockIdx.x & 15;
  const int cslice = blockIdx.x >> 4;
  const int w = tid >> 6, lane = tid & 63;
  const int brow = grp * ROWS + (w & 1) * 16 + (lane & 15);
  const int koff = (lane >> 4) * 8;
  const int j0 = (w >> 1) * 16 + ((lane >> 4) << 2);

  unsigned char* fl = flags + grp * 64;
  unsigned char* myfl = fl + cslice;
  const char* hp0 = (const char*)hbuf + ((size_t)brow * HH + koff) * 2;
  const char* hp1 = hp0 + (size_t)BB * HH * 2;
  char* hw0 = (char*)hbuf + ((size_t)brow * HH + cslice * NHID + j0) * 2;
  char* hw1 = hw0 + (size_t)BB * HH * 2;
  const char* xb = (const char*)inp + ((size_t)brow * TT * FF + koff) * 2;

  float c4[4] = {0.f, 0.f, 0.f, 0.f};
  v4f bb[4];
  float lb4[4] = {0.f, 0.f, 0.f, 0.f};
  unsigned gen = 0;
  int cur = 0;

  // -------- encoder --------
  load_wtile<SCW>(eWhh, eWih, eB, nullptr, cslice, wt, bs);
  __syncthreads();
#pragma unroll
  for (int n = 0; n < 4; ++n) bb[n] = *(const v4f*)&bs[n * 32 + j0];
#pragma unroll 1
  for (int t = 0; t < TT; ++t) {
    ++gen;
    lstm_step<SCW, false>(tid, cslice, cur ? hp1 : hp0, cur ? hw0 : hw1,
                          xb + (size_t)t * FF * 2, nullptr, nullptr, nullptr,
                          wt, bb, c4, fl, myfl, gen);
    cur ^= 1;
  }

  // -------- decoder step 0 --------
  __syncthreads();
  load_wtile<SCW>(dWhh, dWih, dB, nullptr, cslice, wt, bs);
  __syncthreads();
#pragma unroll
  for (int n = 0; n < 4; ++n) bb[n] = *(const v4f*)&bs[n * 32 + j0];
  ++gen;
  lstm_step<SCW, false>(tid, cslice, cur ? hp1 : hp0, cur ? hw0 : hw1,
                        xb + (size_t)(TT - 1) * FF * 2, nullptr, nullptr, nullptr,
                        wt, bb, c4, fl, myfl, gen);
  cur ^= 1;

  // -------- decoder steps 1..47 (folded weights), out_{d-1} rides along --------
  __syncthreads();
  load_wtile<SCH>(wEff, nullptr, nullptr, bEff, cslice, wt, bs);
  __syncthreads();
#pragma unroll
  for (int n = 0; n < 4; ++n) bb[n] = *(const v4f*)&bs[n * 32 + j0];
  if (cslice < 2 && w < 2) {
#pragma unroll
    for (int r = 0; r < 4; ++r)
      lb4[r] = __bfloat162float(linB[cslice * 16 + ((lane >> 4) << 2) + r]);
  }
#pragma unroll 1
  for (int d = 1; d < PP; ++d) {
    ++gen;
    float* op = out + (size_t)brow * PP * FF + (size_t)(d - 1) * FF + cslice * 16 + ((lane >> 4) << 2);
    lstm_step<SCH, true>(tid, cslice, cur ? hp1 : hp0, cur ? hw0 : hw1,
                         nullptr, linW, lb4, op, wt, bb, c4, fl, myfl, gen);
    cur ^= 1;
  }

  // -------- tail: out_47 from final h --------
  if (cslice < 2 && w < 2) {
    u32x4 hb[16];
    coh_load_h(hb, cur ? hp1 : hp0);
    v4f oacc = {0, 0, 0, 0};
#pragma unroll
    for (int kc = 0; kc < KCH; ++kc) {
      union { u32x4 q; v8bf v; } u_; u_.q = hb[kc];
      v8bf al = *(const v8bf*)((const char*)linW +
                 ((size_t)(cslice * 16 + (lane & 15)) * HH + kc * 32 + koff) * 2);
      oacc = __builtin_amdgcn_mfma_f32_16x16x32_bf16(al, u_.v, oacc, 0, 0, 0);
    }
    v4f ovv;
#pragma unroll
    for (int r = 0; r < 4; ++r) ovv[r] = oacc[r] + lb4[r];
    *(v4f*)(out + (size_t)brow * PP * FF + (size_t)(PP - 1) * FF + cslice * 16 + ((lane >> 4) << 2)) = ovv;
  }
}

// ---- setup: zero h0 + flags, b_eff = dec_b + Wih_dec @ lin_b ----
__global__ void setup_misc(const __hip_bfloat16* __restrict__ dWih,
                           const __hip_bfloat16* __restrict__ dB,
                           const __hip_bfloat16* __restrict__ linB,
                           __hip_bfloat16* __restrict__ hbuf,
                           float* __restrict__ bEff, unsigned* __restrict__ flags32) {
  const int idx = blockIdx.x * 256 + threadIdx.x;
  if (idx < BB * HH / 2) ((unsigned*)hbuf)[idx] = 0u;   // zero h ping buffer
  if (idx < 512) flags32[idx] = 0u;                     // zero flag lines
  if (idx < 4 * HH) {
    float a = __bfloat162float(dB[idx]);
#pragma unroll 8
    for (int f = 0; f < FF; ++f)
      a += __bfloat162float(dWih[(size_t)idx * FF + f]) * __bfloat162float(linB[f]);
    bEff[idx] = a;
  }
}

// ---- setup: W_eff[n][k] = Whh_dec[n][k] + sum_f lin_W[f][k] * Wih_dec[n][f] ----
__global__ void setup_weff(const __hip_bfloat16* __restrict__ dWhh,
                           const __hip_bfloat16* __restrict__ dWih,
                           const __hip_bfloat16* __restrict__ linW,
                           __hip_bfloat16* __restrict__ wEff) {
  const int idx = blockIdx.x * 256 + threadIdx.x;
  const int n = idx >> 9, k = idx & 511;
  float a = __bfloat162float(dWhh[idx]);
#pragma unroll 8
  for (int f = 0; f < FF; ++f)
    a += __bfloat162float(linW[(size_t)f * HH + k]) * __bfloat162float(dWih[(size_t)n * FF + f]);
  wEff[idx] = __float2bfloat16(a);
}

extern "C" void kernel_launch(void* const* d_in, const int* in_sizes, int n_in,
                              void* d_out, int out_size, void* d_ws, size_t ws_size,
                              hipStream_t stream) {
  (void)in_sizes; (void)n_in; (void)out_size; (void)ws_size;
  char* ws = (char*)d_ws;
  unsigned*       flag = (unsigned*)ws;                              // @0
  unsigned char*  flags = (unsigned char*)(ws + 256);                // 2 KB (16 x 64B lines)
  float*          bEff = (float*)(ws + 4096);                        // 8 KB
  __hip_bfloat16* hbuf = (__hip_bfloat16*)(ws + 12288);              // 1 MiB (2 x 512x512)
  __hip_bfloat16* wEff = (__hip_bfloat16*)(ws + 12288 + 1048576);    // 2 MiB
  char* cbase = ws + 12288 + 1048576 + 2097152;
  __hip_bfloat16* c_inp  = (__hip_bfloat16*)(cbase);                 // 3,145,728 B
  __hip_bfloat16* c_eWih = (__hip_bfloat16*)(cbase + 3145728);
  __hip_bfloat16* c_eWhh = (__hip_bfloat16*)(cbase + 3276800);
  __hip_bfloat16* c_eB   = (__hip_bfloat16*)(cbase + 5373952);
  __hip_bfloat16* c_dWih = (__hip_bfloat16*)(cbase + 5378048);
  __hip_bfloat16* c_dWhh = (__hip_bfloat16*)(cbase + 5509120);
  __hip_bfloat16* c_dB   = (__hip_bfloat16*)(cbase + 7606272);
  __hip_bfloat16* c_linW = (__hip_bfloat16*)(cbase + 7610368);
  __hip_bfloat16* c_linB = (__hip_bfloat16*)(cbase + 7643136);

  detect_dtype<<<dim3(1), dim3(64), 0, stream>>>((const unsigned short*)d_in[4], flag);

  struct { int idx; __hip_bfloat16* dst; int n; } jobs[9] = {
    {0, c_inp,  BB * TT * FF}, {3, c_eWih, 4 * HH * FF}, {4, c_eWhh, 4 * HH * HH},
    {5, c_eB,   4 * HH},       {6, c_dWih, 4 * HH * FF}, {7, c_dWhh, 4 * HH * HH},
    {8, c_dB,   4 * HH},       {9, c_linW, FF * HH},     {10, c_linB, FF},
  };
  for (int j = 0; j < 9; ++j) {
    int blocks = (jobs[j].n / 8 + 255) / 256;
    canon<<<dim3(blocks), dim3(256), 0, stream>>>(d_in[jobs[j].idx], jobs[j].dst, jobs[j].n, flag);
  }

  setup_misc<<<dim3(512), dim3(256), 0, stream>>>(c_dWih, c_dB, c_linB, hbuf, bEff, (unsigned*)flags);
  setup_weff<<<dim3(4096), dim3(256), 0, stream>>>(c_dWhh, c_dWih, c_linW, wEff);
  seq_main<<<dim3(256), dim3(256), 0, stream>>>(c_inp, c_eWih, c_eWhh, c_eB,
                                                c_dWih, c_dWhh, c_dB,
                                                c_linW, c_linB, wEff, bEff, hbuf, flags,
                                                (float*)d_out);
}